// Round 4
// baseline (137.564 us; speedup 1.0000x reference)
//
#include <hip/hip_runtime.h>

namespace {

constexpr int kNY = 512;
constexpr int kNT = 128;
constexpr int kC  = 128;
constexpr int kEOS = 1;
constexpr int kJT = 64;          // j-tile width in gather kernel
constexpr int kLP = 65;          // padded LDS stride (bank-conflict-free)
constexpr int kD  = 6;           // dp prefetch pipeline depth (rows)

// ---------------------------------------------------------------------------
// Kernel 1: gather + transpose + fold R factors.
// W[b][i][j] = { R0[j]*pred[b,j,tg[i]],  R1'[j]*I[b,j,tg[i]] }  (float2)
// ---------------------------------------------------------------------------
__global__ __launch_bounds__(256, 1) void gather_kernel(
    const float* __restrict__ pred, const float* __restrict__ R,
    const float* __restrict__ I, const int* __restrict__ target,
    float2* __restrict__ W) {
  const int jt = blockIdx.x;        // 0..7
  const int b  = blockIdx.y;        // 0..127
  const int j0 = jt * kJT;
  const int tid = threadIdx.x;

  __shared__ float P[kC * kLP];
  __shared__ float Q[kC * kLP];
  __shared__ int tgs[kNT];

  if (tid < kNT) tgs[tid] = target[b * kNT + tid];

  {
    const int cg = (tid & 31) * 4;   // class offset 0..124
    int jl = tid >> 5;               // 0..7, step 8
    const float* Pb = pred + ((size_t)b * kNY + j0) * kC;
    const float* Ib = I    + ((size_t)b * kNY + j0) * kC;
#pragma unroll
    for (int it = 0; it < 8; ++it, jl += 8) {
      float4 a = *(const float4*)(Pb + (size_t)jl * kC + cg);
      float4 e = *(const float4*)(Ib + (size_t)jl * kC + cg);
      P[(cg + 0) * kLP + jl] = a.x;  P[(cg + 1) * kLP + jl] = a.y;
      P[(cg + 2) * kLP + jl] = a.z;  P[(cg + 3) * kLP + jl] = a.w;
      Q[(cg + 0) * kLP + jl] = e.x;  Q[(cg + 1) * kLP + jl] = e.y;
      Q[(cg + 2) * kLP + jl] = e.z;  Q[(cg + 3) * kLP + jl] = e.w;
    }
  }
  const int l = tid & 63;            // lane
  const int w = tid >> 6;            // wave 0..3
  const int j = j0 + l;
  const float R0l = R[((size_t)b * kNY + j) * 3 + 0];
  const float R1l = (j == kNY - 1) ? 1.0f : R[((size_t)b * kNY + j) * 3 + 1];
  __syncthreads();

#pragma unroll 4
  for (int p = 0; p < 32; ++p) {
    const int i = p * 4 + w;
    const int t = tgs[i];
    float u = R0l * P[t * kLP + l];
    float v = R1l * Q[t * kLP + l];
    W[((size_t)b * kNT + i) * kNY + j] = make_float2(u, v);
  }
}

// ---------------------------------------------------------------------------
// Kernel 2: the DP. One wave per batch, 8 columns per lane, DPP affine scan,
// depth-kD register-prefetch pipeline. __launch_bounds__(64,1) releases the
// full VGPR budget so the backend keeps all kD Frags (96 regs) resident
// instead of collapsing the pipeline to hit its default occupancy target.
// ---------------------------------------------------------------------------
template <int CTRL, int RM>
__device__ __forceinline__ float dppf(float src, float old) {
  return __int_as_float(__builtin_amdgcn_update_dpp(
      __float_as_int(old), __float_as_int(src), CTRL, RM, 0xF, false));
}

// value of `v` in lane-1 (lane 0 -> 0.0f), pure DPP
__device__ __forceinline__ float lane_prev(float v, int lane) {
  float s1  = dppf<0x111, 0xF>(v, 0.0f);   // row_shr:1 (within 16)
  float b15 = dppf<0x142, 0xA>(v, 0.0f);   // lanes 16-31<-15, 48-63<-47
  float b31 = dppf<0x143, 0x4>(v, 0.0f);   // lanes 32-47<-31
  float r = s1;
  r = (lane == 16 || lane == 48) ? b15 : r;
  r = (lane == 32) ? b31 : r;
  return r;
}

struct Frag {
  float u[8];
  float v[8];
};

__device__ __forceinline__ void prefetch_row(const float2* __restrict__ Wrow,
                                             int lane, Frag& f) {
  const float4* p = (const float4*)(Wrow + lane * 8);
#pragma unroll
  for (int k = 0; k < 4; ++k) {
    float4 q = p[k];
    f.u[2 * k + 0] = q.x; f.v[2 * k + 0] = q.y;
    f.u[2 * k + 1] = q.z; f.v[2 * k + 1] = q.w;
  }
}

// inclusive 64-lane affine scan of (A,B), then exclusive-A carry, apply.
__device__ __forceinline__ void scan_apply(const float (&Ap)[8],
                                           const float (&Bp)[8],
                                           float (&x)[8], float& xm1,
                                           int lane) {
  float SA = Ap[7], SB = Bp[7];
#define EP_SCAN_STEP(CTRL, RM)                                   \
  { float a = dppf<CTRL, RM>(SA, 0.0f);                          \
    float bb = dppf<CTRL, RM>(SB, 1.0f);                         \
    SA = fmaf(SB, a, SA); SB *= bb; }
  EP_SCAN_STEP(0x111, 0xF)   // row_shr:1
  EP_SCAN_STEP(0x112, 0xF)   // row_shr:2
  EP_SCAN_STEP(0x114, 0xF)   // row_shr:4
  EP_SCAN_STEP(0x118, 0xF)   // row_shr:8
  EP_SCAN_STEP(0x142, 0xA)   // row_bcast:15 -> rows 1,3
  EP_SCAN_STEP(0x143, 0xC)   // row_bcast:31 -> rows 2,3
#undef EP_SCAN_STEP
  const float carry = lane_prev(SA, lane);
#pragma unroll
  for (int c = 0; c < 8; ++c) x[c] = fmaf(Bp[c], carry, Ap[c]);
  xm1 = carry;
}

__device__ __forceinline__ void dp_row(const Frag& f, bool eos, bool lane0,
                                       const float (&R2m)[8], float (&x)[8],
                                       float& xm1, int lane) {
  float A[8], Bv[8], Ap[8], Bp[8];
  const float um1 = lane_prev(f.u[7], lane);  // U[lane*8-1]
  A[0]  = lane0 ? x[0] * f.v[1] : fmaf(x[0], f.v[0], xm1 * um1);
  Bv[0] = lane0 ? 0.0f : (eos ? 1.0f : R2m[0]);
#pragma unroll
  for (int c = 1; c < 8; ++c) {
    A[c]  = fmaf(x[c], f.v[c], x[c - 1] * f.u[c - 1]);
    Bv[c] = eos ? 1.0f : R2m[c];
  }
  Ap[0] = A[0]; Bp[0] = Bv[0];
#pragma unroll
  for (int c = 1; c < 8; ++c) {
    Ap[c] = fmaf(Bv[c], Ap[c - 1], A[c]);
    Bp[c] = Bv[c] * Bp[c - 1];
  }
  scan_apply(Ap, Bp, x, xm1, lane);
}

__global__ __launch_bounds__(64, 1) void dp_kernel(
    const float2* __restrict__ W, const float* __restrict__ R,
    const int* __restrict__ target, float* __restrict__ out) {
  const int b = blockIdx.x;
  const int lane = threadIdx.x;
  const bool lane0 = (lane == 0);

  const int ta = target[b * kNT + lane];
  const int tb = target[b * kNT + 64 + lane];
  const unsigned long long eosLo = __ballot(ta == kEOS);
  const unsigned long long eosHi = __ballot(tb == kEOS);

  const float* Rb = R + (size_t)b * kNY * 3;
  float R2m[8], R2o[8];
#pragma unroll
  for (int c = 0; c < 8; ++c) R2o[c] = Rb[(lane * 8 + c) * 3 + 2];
  R2m[0] = lane0 ? 0.0f : Rb[(lane * 8 - 1) * 3 + 2];
#pragma unroll
  for (int c = 1; c < 8; ++c) R2m[c] = R2o[c - 1];

  const float2* Wb = W + (size_t)b * kNT * kNY;

  // fill the pipeline: rows 0..kD-1, loads pinned by memory clobbers
  Frag f[kD];
#pragma unroll
  for (int r = 0; r < kD; ++r) {
    prefetch_row(Wb + (size_t)r * kNY, lane, f[r]);
    asm volatile("" ::: "memory");
  }

  float x[8];
  float xm1 = 0.0f;

  // ---- row 0: ep[0,0]=1; ep[0,j]=ep[0,j-1] * (eos0 ? 1 : R2[j]) ----
  {
    const bool eos0 = (eosLo & 1ull) != 0ull;
    float A[8], Bv[8], Ap[8], Bp[8];
    A[0]  = lane0 ? 1.0f : 0.0f;
    Bv[0] = lane0 ? 0.0f : (eos0 ? 1.0f : R2o[0]);
#pragma unroll
    for (int c = 1; c < 8; ++c) { A[c] = 0.0f; Bv[c] = eos0 ? 1.0f : R2o[c]; }
    Ap[0] = A[0]; Bp[0] = Bv[0];
#pragma unroll
    for (int c = 1; c < 8; ++c) {
      Ap[c] = fmaf(Bv[c], Ap[c - 1], A[c]);
      Bp[c] = Bv[c] * Bp[c - 1];
    }
    scan_apply(Ap, Bp, x, xm1, lane);
  }

  auto eosAt = [&](int i) -> bool {
    return ((i < 64 ? (eosLo >> i) : (eosHi >> (i - 64))) & 1ull) != 0ull;
  };

  // rows i = 1..126 in 21 groups of kD; iteration i consumes W row i-1
  // (slot (i-1)%kD) and reloads that slot with row min(i+kD-1, 126).
  for (int g = 0; g < 21; ++g) {
#pragma unroll
    for (int r = 0; r < kD; ++r) {
      const int i = 1 + g * kD + r;
      dp_row(f[r], eosAt(i), lane0, R2m, x, xm1, lane);
      int nr = i + kD - 1;
      if (nr > 126) nr = 126;
      prefetch_row(Wb + (size_t)nr * kNY, lane, f[r]);
      asm volatile("" ::: "memory");
    }
  }
  // tail: row 127 consumes W row 126 = slot (126)%6 = 0
  dp_row(f[0], eosAt(127), lane0, R2m, x, xm1, lane);

  if (lane == 63) out[b] = x[7];
}

// ---------------------------------------------------------------------------
// Fallback (R1 kernel) if workspace is too small for W.
// ---------------------------------------------------------------------------
__device__ __forceinline__ float block_affine_scan(
    float A, float Bv, int lane, int wave, float* wAs, float* wBs) {
#pragma unroll
  for (int d = 1; d < 64; d <<= 1) {
    float Au = __shfl_up(A, (unsigned)d, 64);
    float Bu = __shfl_up(Bv, (unsigned)d, 64);
    if (lane >= d) { A = fmaf(Bv, Au, A); Bv *= Bu; }
  }
  if (lane == 63) { wAs[wave] = A; wBs[wave] = Bv; }
  __syncthreads();
  float pA = 0.0f;
  for (int w = 0; w < wave; ++w) pA = fmaf(wBs[w], pA, wAs[w]);
  __syncthreads();
  return fmaf(Bv, pA, A);
}

__global__ __launch_bounds__(kNY) void ep_forward_kernel(
    const float* __restrict__ pred, const float* __restrict__ R,
    const float* __restrict__ I, const int* __restrict__ target,
    float* __restrict__ out) {
  const int b = blockIdx.x;
  const int j = threadIdx.x;
  const int lane = j & 63;
  const int wave = j >> 6;

  __shared__ int tg[kNT];
  __shared__ float wAs[8], wBs[8], uBs[8];

  const float* Rb = R + (size_t)b * kNY * 3;
  const float* Pb = pred + (size_t)b * kNY * kC;
  const float* Ib = I + (size_t)b * kNY * kC;

  const float R0  = Rb[j * 3 + 0];
  const float R1  = (j == kNY - 1) ? 1.0f : Rb[j * 3 + 1];
  const float R2  = Rb[j * 3 + 2];
  const float R2m = (j >= 1) ? Rb[(j - 1) * 3 + 2] : 0.0f;

  if (j < kNT) tg[j] = target[b * kNT + j];
  __syncthreads();

  const int t0 = tg[0];
  float A0 = (j == 0) ? 1.0f : 0.0f;
  float B0 = (j == 0) ? 0.0f : ((t0 == kEOS) ? 1.0f : R2);
  float ep = block_affine_scan(A0, B0, lane, wave, wAs, wBs);
  float gp = Pb[j * kC + t0];
  float gi = Ib[j * kC + t0];

  for (int i = 1; i < kNT; ++i) {
    const int td = tg[i];
    const float v = R1 * gi;
    const float u = ep * (R0 * gp);
    const int tcn = tg[i];
    gp = Pb[j * kC + tcn];
    gi = Ib[j * kC + tcn];
    if (lane == 63) uBs[wave] = u;
    __syncthreads();
    float uUp = __shfl_up(u, 1u, 64);
    if (lane == 0) uUp = (wave == 0) ? 0.0f : uBs[wave - 1];
    const float v1 = __shfl(v, 1, 64);
    float A, Bv;
    if (j == 0) { A = ep * v1; Bv = 0.0f; }
    else { A = fmaf(ep, v, uUp); Bv = (td == kEOS) ? 1.0f : R2m; }
    ep = block_affine_scan(A, Bv, lane, wave, wAs, wBs);
  }
  if (j == kNY - 1) out[b] = ep;
}

}  // namespace

extern "C" void kernel_launch(void* const* d_in, const int* in_sizes, int n_in,
                              void* d_out, int out_size, void* d_ws, size_t ws_size,
                              hipStream_t stream) {
  const float* pred = (const float*)d_in[0];
  const float* R    = (const float*)d_in[1];
  const float* I    = (const float*)d_in[2];
  const int* target = (const int*)d_in[3];
  float* out = (float*)d_out;
  (void)in_sizes; (void)n_in; (void)out_size;

  const size_t needW = (size_t)128 * kNT * kNY * sizeof(float2);  // 64 MB
  if (ws_size >= needW) {
    float2* W = (float2*)d_ws;
    gather_kernel<<<dim3(8, 128), dim3(256), 0, stream>>>(pred, R, I, target, W);
    dp_kernel<<<dim3(128), dim3(64), 0, stream>>>(W, R, target, out);
  } else {
    ep_forward_kernel<<<dim3(128), dim3(kNY), 0, stream>>>(pred, R, I, target, out);
  }
}

// Round 5
// 137.355 us; speedup vs baseline: 1.0015x; 1.0015x over previous
//
#include <hip/hip_runtime.h>

namespace {

constexpr int kNY = 512;
constexpr int kNT = 128;
constexpr int kC  = 128;
constexpr int kEOS = 1;
constexpr int kJT = 64;          // j-tile width in gather kernel
constexpr int kLP = 65;          // padded LDS stride (bank-conflict-free)

typedef float f4 __attribute__((ext_vector_type(4)));

// ---------------------------------------------------------------------------
// Kernel 1: gather + transpose + fold R factors.
// W[b][i][j] = { R0[j]*pred[b,j,tg[i]],  R1'[j]*I[b,j,tg[i]] }  (float2)
// ---------------------------------------------------------------------------
__global__ __launch_bounds__(256, 1) void gather_kernel(
    const float* __restrict__ pred, const float* __restrict__ R,
    const float* __restrict__ I, const int* __restrict__ target,
    float2* __restrict__ W) {
  const int jt = blockIdx.x;        // 0..7
  const int b  = blockIdx.y;        // 0..127
  const int j0 = jt * kJT;
  const int tid = threadIdx.x;

  __shared__ float P[kC * kLP];
  __shared__ float Q[kC * kLP];
  __shared__ int tgs[kNT];

  if (tid < kNT) tgs[tid] = target[b * kNT + tid];

  {
    const int cg = (tid & 31) * 4;   // class offset 0..124
    int jl = tid >> 5;               // 0..7, step 8
    const float* Pb = pred + ((size_t)b * kNY + j0) * kC;
    const float* Ib = I    + ((size_t)b * kNY + j0) * kC;
#pragma unroll
    for (int it = 0; it < 8; ++it, jl += 8) {
      float4 a = *(const float4*)(Pb + (size_t)jl * kC + cg);
      float4 e = *(const float4*)(Ib + (size_t)jl * kC + cg);
      P[(cg + 0) * kLP + jl] = a.x;  P[(cg + 1) * kLP + jl] = a.y;
      P[(cg + 2) * kLP + jl] = a.z;  P[(cg + 3) * kLP + jl] = a.w;
      Q[(cg + 0) * kLP + jl] = e.x;  Q[(cg + 1) * kLP + jl] = e.y;
      Q[(cg + 2) * kLP + jl] = e.z;  Q[(cg + 3) * kLP + jl] = e.w;
    }
  }
  const int l = tid & 63;            // lane
  const int w = tid >> 6;            // wave 0..3
  const int j = j0 + l;
  const float R0l = R[((size_t)b * kNY + j) * 3 + 0];
  const float R1l = (j == kNY - 1) ? 1.0f : R[((size_t)b * kNY + j) * 3 + 1];
  __syncthreads();

#pragma unroll 4
  for (int p = 0; p < 32; ++p) {
    const int i = p * 4 + w;
    const int t = tgs[i];
    float u = R0l * P[t * kLP + l];
    float v = R1l * Q[t * kLP + l];
    W[((size_t)b * kNT + i) * kNY + j] = make_float2(u, v);
  }
}

// ---------------------------------------------------------------------------
// Kernel 2: the DP. One wave per batch, 8 columns per lane, DPP affine scan.
// Staging loads are inline-asm global_load_dwordx4 into register quads the
// scheduler cannot sink (invariant-load sinking defeated C++-level pinning
// in R2-R4). Explicit s_waitcnt vmcnt(28) gates consumption: depth-8 row
// ring x 4 loads = 32 outstanding; wait until the oldest row's 4 are back.
// ---------------------------------------------------------------------------
template <int CTRL, int RM>
__device__ __forceinline__ float dppf(float src, float old) {
  return __int_as_float(__builtin_amdgcn_update_dpp(
      __float_as_int(old), __float_as_int(src), CTRL, RM, 0xF, false));
}

// value of `v` in lane-1 (lane 0 -> 0.0f), pure DPP
__device__ __forceinline__ float lane_prev(float v, int lane) {
  float s1  = dppf<0x111, 0xF>(v, 0.0f);   // row_shr:1 (within 16)
  float b15 = dppf<0x142, 0xA>(v, 0.0f);   // lanes 16-31<-15, 48-63<-47
  float b31 = dppf<0x143, 0x4>(v, 0.0f);   // lanes 32-47<-31
  float r = s1;
  r = (lane == 16 || lane == 48) ? b15 : r;
  r = (lane == 32) ? b31 : r;
  return r;
}

struct FragR {
  f4 q0, q1, q2, q3;   // u[2k]=qk.x v[2k]=qk.y u[2k+1]=qk.z v[2k+1]=qk.w
};

__device__ __forceinline__ void prefetch_row_asm(const char* addr, FragR& f) {
  asm volatile(
      "global_load_dwordx4 %0, %4, off\n\t"
      "global_load_dwordx4 %1, %4, off offset:16\n\t"
      "global_load_dwordx4 %2, %4, off offset:32\n\t"
      "global_load_dwordx4 %3, %4, off offset:48"
      : "=v"(f.q0), "=v"(f.q1), "=v"(f.q2), "=v"(f.q3)
      : "v"(addr));
}

// wait until this frag's 4 loads (the oldest outstanding) have landed
__device__ __forceinline__ void wait_frag28(FragR& f) {
  asm volatile("s_waitcnt vmcnt(28)"
               : "+v"(f.q0), "+v"(f.q1), "+v"(f.q2), "+v"(f.q3));
}

// inclusive 64-lane affine scan of (A,B), then exclusive-A carry, apply.
__device__ __forceinline__ void scan_apply(const float (&Ap)[8],
                                           const float (&Bp)[8],
                                           float (&x)[8], float& xm1,
                                           int lane) {
  float SA = Ap[7], SB = Bp[7];
#define EP_SCAN_STEP(CTRL, RM)                                   \
  { float a = dppf<CTRL, RM>(SA, 0.0f);                          \
    float bb = dppf<CTRL, RM>(SB, 1.0f);                         \
    SA = fmaf(SB, a, SA); SB *= bb; }
  EP_SCAN_STEP(0x111, 0xF)   // row_shr:1
  EP_SCAN_STEP(0x112, 0xF)   // row_shr:2
  EP_SCAN_STEP(0x114, 0xF)   // row_shr:4
  EP_SCAN_STEP(0x118, 0xF)   // row_shr:8
  EP_SCAN_STEP(0x142, 0xA)   // row_bcast:15 -> rows 1,3
  EP_SCAN_STEP(0x143, 0xC)   // row_bcast:31 -> rows 2,3
#undef EP_SCAN_STEP
  const float carry = lane_prev(SA, lane);
#pragma unroll
  for (int c = 0; c < 8; ++c) x[c] = fmaf(Bp[c], carry, Ap[c]);
  xm1 = carry;
}

__device__ __forceinline__ void dp_row(const FragR& fq, bool eos, bool lane0,
                                       const float (&R2m)[8], float (&x)[8],
                                       float& xm1, int lane) {
  float u[8], v[8];
  u[0] = fq.q0.x; v[0] = fq.q0.y; u[1] = fq.q0.z; v[1] = fq.q0.w;
  u[2] = fq.q1.x; v[2] = fq.q1.y; u[3] = fq.q1.z; v[3] = fq.q1.w;
  u[4] = fq.q2.x; v[4] = fq.q2.y; u[5] = fq.q2.z; v[5] = fq.q2.w;
  u[6] = fq.q3.x; v[6] = fq.q3.y; u[7] = fq.q3.z; v[7] = fq.q3.w;

  float A[8], Bv[8], Ap[8], Bp[8];
  const float um1 = lane_prev(u[7], lane);  // U[lane*8-1]
  A[0]  = lane0 ? x[0] * v[1] : fmaf(x[0], v[0], xm1 * um1);
  Bv[0] = lane0 ? 0.0f : (eos ? 1.0f : R2m[0]);
#pragma unroll
  for (int c = 1; c < 8; ++c) {
    A[c]  = fmaf(x[c], v[c], x[c - 1] * u[c - 1]);
    Bv[c] = eos ? 1.0f : R2m[c];
  }
  Ap[0] = A[0]; Bp[0] = Bv[0];
#pragma unroll
  for (int c = 1; c < 8; ++c) {
    Ap[c] = fmaf(Bv[c], Ap[c - 1], A[c]);
    Bp[c] = Bv[c] * Bp[c - 1];
  }
  scan_apply(Ap, Bp, x, xm1, lane);
}

__global__ __launch_bounds__(64, 1) void dp_kernel(
    const float2* __restrict__ W, const float* __restrict__ R,
    const int* __restrict__ target, float* __restrict__ out) {
  const int b = blockIdx.x;
  const int lane = threadIdx.x;
  const bool lane0 = (lane == 0);

  const int ta = target[b * kNT + lane];
  const int tb = target[b * kNT + 64 + lane];
  const unsigned long long eosLo = __ballot(ta == kEOS);
  const unsigned long long eosHi = __ballot(tb == kEOS);

  const float* Rb = R + (size_t)b * kNY * 3;
  float R2m[8], R2o[8];
#pragma unroll
  for (int c = 0; c < 8; ++c) R2o[c] = Rb[(lane * 8 + c) * 3 + 2];
  R2m[0] = lane0 ? 0.0f : Rb[(lane * 8 - 1) * 3 + 2];
#pragma unroll
  for (int c = 1; c < 8; ++c) R2m[c] = R2o[c - 1];

  // per-lane base address into W[b]: row r at base + r*4096
  const char* base = (const char*)(W + (size_t)b * kNT * kNY + lane * 8);

  float x[8];
  float xm1 = 0.0f;

  // ---- row 0: ep[0,0]=1; ep[0,j]=ep[0,j-1] * (eos0 ? 1 : R2[j]) ----
  {
    const bool eos0 = (eosLo & 1ull) != 0ull;
    float A[8], Bv[8], Ap[8], Bp[8];
    A[0]  = lane0 ? 1.0f : 0.0f;
    Bv[0] = lane0 ? 0.0f : (eos0 ? 1.0f : R2o[0]);
#pragma unroll
    for (int c = 1; c < 8; ++c) { A[c] = 0.0f; Bv[c] = eos0 ? 1.0f : R2o[c]; }
    Ap[0] = A[0]; Bp[0] = Bv[0];
#pragma unroll
    for (int c = 1; c < 8; ++c) {
      Ap[c] = fmaf(Bv[c], Ap[c - 1], A[c]);
      Bp[c] = Bv[c] * Bp[c - 1];
    }
    scan_apply(Ap, Bp, x, xm1, lane);
  }

  auto eosAt = [&](int i) -> bool {
    return ((i < 64 ? (eosLo >> i) : (eosHi >> (i - 64))) & 1ull) != 0ull;
  };

  // drain prologue VMEM so our vmcnt accounting is exact
  asm volatile("s_waitcnt vmcnt(0)" ::: "memory");

  // fill: issue rows 0..7 (32 loads outstanding)
  FragR f[8];
#pragma unroll
  for (int r = 0; r < 8; ++r)
    prefetch_row_asm(base + (size_t)r * (kNY * 8), f[r]);

  // consume W rows r=0..126 (DP rows i=r+1); each step waits for the oldest
  // row's 4 loads, runs the row, and re-issues that slot with row r+8
  // (clamped to 126 so the outstanding count stays exactly 32).
  auto step = [&](int r, FragR& fr) {
    wait_frag28(fr);
    dp_row(fr, eosAt(r + 1), lane0, R2m, x, xm1, lane);
    int nr = r + 8;
    if (nr > 126) nr = 126;
    prefetch_row_asm(base + (size_t)nr * (kNY * 8), fr);
  };

  for (int g = 0; g < 15; ++g) {   // rows 0..119
#pragma unroll
    for (int rr = 0; rr < 8; ++rr) step(g * 8 + rr, f[rr]);
  }
#pragma unroll
  for (int rr = 0; rr < 7; ++rr) step(120 + rr, f[rr]);  // rows 120..126

  if (lane == 63) out[b] = x[7];
}

// ---------------------------------------------------------------------------
// Fallback (R1 kernel) if workspace is too small for W.
// ---------------------------------------------------------------------------
__device__ __forceinline__ float block_affine_scan(
    float A, float Bv, int lane, int wave, float* wAs, float* wBs) {
#pragma unroll
  for (int d = 1; d < 64; d <<= 1) {
    float Au = __shfl_up(A, (unsigned)d, 64);
    float Bu = __shfl_up(Bv, (unsigned)d, 64);
    if (lane >= d) { A = fmaf(Bv, Au, A); Bv *= Bu; }
  }
  if (lane == 63) { wAs[wave] = A; wBs[wave] = Bv; }
  __syncthreads();
  float pA = 0.0f;
  for (int w = 0; w < wave; ++w) pA = fmaf(wBs[w], pA, wAs[w]);
  __syncthreads();
  return fmaf(Bv, pA, A);
}

__global__ __launch_bounds__(kNY) void ep_forward_kernel(
    const float* __restrict__ pred, const float* __restrict__ R,
    const float* __restrict__ I, const int* __restrict__ target,
    float* __restrict__ out) {
  const int b = blockIdx.x;
  const int j = threadIdx.x;
  const int lane = j & 63;
  const int wave = j >> 6;

  __shared__ int tg[kNT];
  __shared__ float wAs[8], wBs[8], uBs[8];

  const float* Rb = R + (size_t)b * kNY * 3;
  const float* Pb = pred + (size_t)b * kNY * kC;
  const float* Ib = I + (size_t)b * kNY * kC;

  const float R0  = Rb[j * 3 + 0];
  const float R1  = (j == kNY - 1) ? 1.0f : Rb[j * 3 + 1];
  const float R2  = Rb[j * 3 + 2];
  const float R2m = (j >= 1) ? Rb[(j - 1) * 3 + 2] : 0.0f;

  if (j < kNT) tg[j] = target[b * kNT + j];
  __syncthreads();

  const int t0 = tg[0];
  float A0 = (j == 0) ? 1.0f : 0.0f;
  float B0 = (j == 0) ? 0.0f : ((t0 == kEOS) ? 1.0f : R2);
  float ep = block_affine_scan(A0, B0, lane, wave, wAs, wBs);
  float gp = Pb[j * kC + t0];
  float gi = Ib[j * kC + t0];

  for (int i = 1; i < kNT; ++i) {
    const int td = tg[i];
    const float v = R1 * gi;
    const float u = ep * (R0 * gp);
    const int tcn = tg[i];
    gp = Pb[j * kC + tcn];
    gi = Ib[j * kC + tcn];
    if (lane == 63) uBs[wave] = u;
    __syncthreads();
    float uUp = __shfl_up(u, 1u, 64);
    if (lane == 0) uUp = (wave == 0) ? 0.0f : uBs[wave - 1];
    const float v1 = __shfl(v, 1, 64);
    float A, Bv;
    if (j == 0) { A = ep * v1; Bv = 0.0f; }
    else { A = fmaf(ep, v, uUp); Bv = (td == kEOS) ? 1.0f : R2m; }
    ep = block_affine_scan(A, Bv, lane, wave, wAs, wBs);
  }
  if (j == kNY - 1) out[b] = ep;
}

}  // namespace

extern "C" void kernel_launch(void* const* d_in, const int* in_sizes, int n_in,
                              void* d_out, int out_size, void* d_ws, size_t ws_size,
                              hipStream_t stream) {
  const float* pred = (const float*)d_in[0];
  const float* R    = (const float*)d_in[1];
  const float* I    = (const float*)d_in[2];
  const int* target = (const int*)d_in[3];
  float* out = (float*)d_out;
  (void)in_sizes; (void)n_in; (void)out_size;

  const size_t needW = (size_t)128 * kNT * kNY * sizeof(float2);  // 64 MB
  if (ws_size >= needW) {
    float2* W = (float2*)d_ws;
    gather_kernel<<<dim3(8, 128), dim3(256), 0, stream>>>(pred, R, I, target, W);
    dp_kernel<<<dim3(128), dim3(64), 0, stream>>>(W, R, target, out);
  } else {
    ep_forward_kernel<<<dim3(128), dim3(kNY), 0, stream>>>(pred, R, I, target, out);
  }
}